// Round 6
// baseline (598.374 us; speedup 1.0000x reference)
//
#include <hip/hip_runtime.h>
#include <hip/hip_fp16.h>

// Two-phase split to unmix read/write streams at the memory system.
// P1: A,B (512 MiB) -> packed u16 fp16 sums (8 MiB, d_ws). ~pure READ stream.
// P2: u16 sums (8 MiB, cache-resident) -> 256 MiB bit-float output. ~pure
//     WRITE stream, full-line coalesced stores.
// Total demand bytes unchanged vs fused (~784 MiB) — this isolates whether
// the observed ~4.15 TB/s plateau is caused by 2R:1W stream mixing / L3
// thrash (768 MiB working set through 256 MiB L3).
// Bit extraction from 0.0f/1.0f via (u>>23)&1 (1.0f = 0x3F800000), no cvt.
// fp16 add via exact fp32 add + RNE cvt (bit-exact, Figueroa 24 >= 2*11+2).

__global__ __launch_bounds__(256) void spike_p1_sum_kernel(
    const uint4* __restrict__ A, const uint4* __restrict__ B,
    unsigned short* __restrict__ S, int nrows)
{
    int r = blockIdx.x * blockDim.x + threadIdx.x;
    if (r >= nrows) return;
    const size_t base = (size_t)r * 4;

    uint4 a0 = A[base + 0], a1 = A[base + 1], a2 = A[base + 2], a3 = A[base + 3];
    uint4 b0 = B[base + 0], b1 = B[base + 1], b2 = B[base + 2], b3 = B[base + 3];

    // MSB-first pack; bit j = (word>>23)&1 placed at 15-j.
    uint32_t ua =
        (((a0.x >> 23) & 1u) << 15) | (((a0.y >> 23) & 1u) << 14) |
        (((a0.z >> 23) & 1u) << 13) | (((a0.w >> 23) & 1u) << 12) |
        (((a1.x >> 23) & 1u) << 11) | (((a1.y >> 23) & 1u) << 10) |
        (((a1.z >> 23) & 1u) <<  9) | (((a1.w >> 23) & 1u) <<  8) |
        (((a2.x >> 23) & 1u) <<  7) | (((a2.y >> 23) & 1u) <<  6) |
        (((a2.z >> 23) & 1u) <<  5) | (((a2.w >> 23) & 1u) <<  4) |
        (((a3.x >> 23) & 1u) <<  3) | (((a3.y >> 23) & 1u) <<  2) |
        (((a3.z >> 23) & 1u) <<  1) |  ((a3.w >> 23) & 1u);
    uint32_t ub =
        (((b0.x >> 23) & 1u) << 15) | (((b0.y >> 23) & 1u) << 14) |
        (((b0.z >> 23) & 1u) << 13) | (((b0.w >> 23) & 1u) << 12) |
        (((b1.x >> 23) & 1u) << 11) | (((b1.y >> 23) & 1u) << 10) |
        (((b1.z >> 23) & 1u) <<  9) | (((b1.w >> 23) & 1u) <<  8) |
        (((b2.x >> 23) & 1u) <<  7) | (((b2.y >> 23) & 1u) <<  6) |
        (((b2.z >> 23) & 1u) <<  5) | (((b2.w >> 23) & 1u) <<  4) |
        (((b3.x >> 23) & 1u) <<  3) | (((b3.y >> 23) & 1u) <<  2) |
        (((b3.z >> 23) & 1u) <<  1) |  ((b3.w >> 23) & 1u);

    float fa = __half2float(__ushort_as_half((unsigned short)ua));
    float fb = __half2float(__ushort_as_half((unsigned short)ub));
    S[r] = __half_as_ushort(__float2half_rn(fa + fb));
}

__global__ __launch_bounds__(256) void spike_p2_expand_kernel(
    const unsigned short* __restrict__ S, float4* __restrict__ O, int nf4)
{
    const int lane = threadIdx.x & 63;
    const int waveBase = ((blockIdx.x * blockDim.x + threadIdx.x) >> 6) * 256;
    const int sh = 12 - 4 * (lane & 3);   // this lane's quarter, MSB-first
    const int idx = waveBase + lane;

    if (waveBase + 255 < nf4) {           // wave-uniform fast path
        uint32_t us[4];
        #pragma unroll
        for (int k = 0; k < 4; ++k) us[k] = S[(idx + k * 64) >> 2];
        #pragma unroll
        for (int k = 0; k < 4; ++k) {
            uint32_t ns = (us[k] >> sh) & 0xFu;
            float4 o;
            o.x = (float)((ns >> 3) & 1u);
            o.y = (float)((ns >> 2) & 1u);
            o.z = (float)((ns >> 1) & 1u);
            o.w = (float)( ns       & 1u);
            O[idx + k * 64] = o;          // 1 KiB contiguous per wave instr
        }
    } else {                              // tail (not hit at N=4194304)
        for (int k = 0; k < 4; ++k) {
            int f4 = idx + k * 64;
            if (f4 < nf4) {
                uint32_t ns = ((uint32_t)S[f4 >> 2] >> sh) & 0xFu;
                float4 o;
                o.x = (float)((ns >> 3) & 1u);
                o.y = (float)((ns >> 2) & 1u);
                o.z = (float)((ns >> 1) & 1u);
                o.w = (float)( ns       & 1u);
                O[f4] = o;
            }
        }
    }
}

// Fallback (R2 fused kernel) if ws_size can't hold the u16 sums.
__global__ __launch_bounds__(256) void spike_fused_kernel(
    const uint4* __restrict__ A, const uint4* __restrict__ B,
    float4* __restrict__ O, int nf4)
{
    const int lane = threadIdx.x & 63;
    const int waveBase = ((blockIdx.x * blockDim.x + threadIdx.x) >> 6) * 256;
    const int sh = 12 - 4 * (lane & 3);
    const int idx = waveBase + lane;

    for (int k = 0; k < 4; ++k) {
        int f4 = idx + k * 64;
        uint32_t ua = 0, ub = 0;
        if (f4 < nf4) {
            uint4 a = A[f4], b = B[f4];
            ua = (((a.x >> 20) & 8u) | ((a.y >> 21) & 4u) |
                  ((a.z >> 22) & 2u) | ((a.w >> 23) & 1u)) << sh;
            ub = (((b.x >> 20) & 8u) | ((b.y >> 21) & 4u) |
                  ((b.z >> 22) & 2u) | ((b.w >> 23) & 1u)) << sh;
        }
        ua |= (uint32_t)__shfl_xor((int)ua, 1);
        ua |= (uint32_t)__shfl_xor((int)ua, 2);
        ub |= (uint32_t)__shfl_xor((int)ub, 1);
        ub |= (uint32_t)__shfl_xor((int)ub, 2);
        float fa = __half2float(__ushort_as_half((unsigned short)ua));
        float fb = __half2float(__ushort_as_half((unsigned short)ub));
        uint32_t us = (uint32_t)__half_as_ushort(__float2half_rn(fa + fb));
        uint32_t ns = (us >> sh) & 0xFu;
        float4 o;
        o.x = (float)((ns >> 3) & 1u);
        o.y = (float)((ns >> 2) & 1u);
        o.z = (float)((ns >> 1) & 1u);
        o.w = (float)( ns       & 1u);
        if (f4 < nf4) O[f4] = o;
    }
}

extern "C" void kernel_launch(void* const* d_in, const int* in_sizes, int n_in,
                              void* d_out, int out_size, void* d_ws, size_t ws_size,
                              hipStream_t stream) {
    int nrows = in_sizes[0] / 16;
    int nf4 = nrows * 4;
    int block = 256;

    if (ws_size >= (size_t)nrows * sizeof(unsigned short)) {
        unsigned short* S = (unsigned short*)d_ws;
        int grid1 = (nrows + block - 1) / block;
        spike_p1_sum_kernel<<<grid1, block, 0, stream>>>(
            (const uint4*)d_in[0], (const uint4*)d_in[1], S, nrows);
        int grid2 = ((nf4 + 3) / 4 + block - 1) / block;
        spike_p2_expand_kernel<<<grid2, block, 0, stream>>>(S, (float4*)d_out, nf4);
    } else {
        int grid = ((nf4 + 3) / 4 + block - 1) / block;
        spike_fused_kernel<<<grid, block, 0, stream>>>(
            (const uint4*)d_in[0], (const uint4*)d_in[1], (float4*)d_out, nf4);
    }
}

// Round 7
// 578.823 us; speedup vs baseline: 1.0338x; 1.0338x over previous
//
#include <hip/hip_runtime.h>
#include <hip/hip_fp16.h>

// Best-measured structure (R2): fully coalesced, serialized per-k.
// Every vmem instr: lane i at base + i*16B (1 KiB/wave/instr).
// Row gather in-register: lane L holds quarter (L&3) of row k*16+(L>>2);
// nibbles OR-combined across the 4-lane group via shfl_xor(1)/shfl_xor(2)
// (DPP quad-perm). All 4 lanes redundantly compute the fp16 add (VALU ~90%
// idle), each extracts its own quarter of the sum -> coalesced cached store.
// Bits extracted from 0.0f/1.0f via (u>>23)&1 (1.0f = 0x3F800000) - no v_cvt.
// fp16 add via exact fp32 add + RNE cvt (bit-exact, Figueroa 24 >= 2*11+2).
//
// Measured plateau: ~190 us kernel = 768 MiB true demand at ~4.15 TB/s.
// Read path on this device never exceeds ~3.4 TB/s (m13 copy read-side 3.15;
// R6 pure-read phase ~3.4) -> 512 MiB reads floor ~148 us + write
// interference ~45 us. Coalescing/MLP/occupancy/persistence/NT/stream-split
// all within +-5% of this point.

__global__ __launch_bounds__(256) void spike_fp16_add_kernel(
    const uint4* __restrict__ A, const uint4* __restrict__ B,
    float4* __restrict__ O, int nf4)   // nf4 = total float4 count = nrows*4
{
    const int lane = threadIdx.x & 63;
    const int waveBase = ((blockIdx.x * blockDim.x + threadIdx.x) >> 6) * 256;
    const int sh = 12 - 4 * (lane & 3); // MSB-first nibble position for this quarter

    #pragma unroll
    for (int k = 0; k < 4; ++k) {
        const int f4 = waveBase + k * 64 + lane;
        if (f4 >= nf4) return;

        uint4 a = A[f4];
        uint4 b = B[f4];

        // pack quarter-row bits (0x00000000 / 0x3F800000) into a nibble, MSB first
        uint32_t ua = ((((a.x >> 20) & 8u) | ((a.y >> 21) & 4u) |
                        ((a.z >> 22) & 2u) | ((a.w >> 23) & 1u)) << sh);
        uint32_t ub = ((((b.x >> 20) & 8u) | ((b.y >> 21) & 4u) |
                        ((b.z >> 22) & 2u) | ((b.w >> 23) & 1u)) << sh);

        // OR-combine nibbles across the 4-lane group (lanes 4m..4m+3)
        ua |= (uint32_t)__shfl_xor((int)ua, 1);
        ua |= (uint32_t)__shfl_xor((int)ua, 2);
        ub |= (uint32_t)__shfl_xor((int)ub, 1);
        ub |= (uint32_t)__shfl_xor((int)ub, 2);

        // fp16 add via exact fp32 add + RNE convert (bit-exact)
        float fa = __half2float(__ushort_as_half((unsigned short)ua));
        float fb = __half2float(__ushort_as_half((unsigned short)ub));
        uint32_t us = (uint32_t)__half_as_ushort(__float2half_rn(fa + fb));

        // this lane's quarter of the sum, MSB first
        uint32_t ns = (us >> sh) & 0xFu;
        float4 o;
        o.x = (float)((ns >> 3) & 1u);
        o.y = (float)((ns >> 2) & 1u);
        o.z = (float)((ns >> 1) & 1u);
        o.w = (float)( ns       & 1u);

        O[f4] = o;
    }
}

extern "C" void kernel_launch(void* const* d_in, const int* in_sizes, int n_in,
                              void* d_out, int out_size, void* d_ws, size_t ws_size,
                              hipStream_t stream) {
    const uint4* A = (const uint4*)d_in[0];
    const uint4* B = (const uint4*)d_in[1];
    float4* O = (float4*)d_out;

    int nf4 = in_sizes[0] / 4;          // total float4s per input
    int block = 256;
    int threads = (nf4 + 3) / 4;        // each thread handles 4 float4s
    int grid = (threads + block - 1) / block;
    spike_fp16_add_kernel<<<grid, block, 0, stream>>>(A, B, O, nf4);
}